// Round 2
// baseline (900.144 us; speedup 1.0000x reference)
//
#include <hip/hip_runtime.h>

#define NN 50000
#define EE 800000
#define BB 4096
#define SCAN_BLK 49   // ceil(50000/1024)

// f32 weight-table offsets (elements)
#define OFF_T1W 0
#define OFF_T1B 16384
#define OFF_GW1 16448
#define OFF_GB1 16832
#define OFF_HW1 16848
#define OFF_GW2 29136
#define OFF_GB2 30288
#define OFF_HW2 30304
#define OFF_T2W 67168
#define OFF_T2B 112224
#define OFF_T3W 112288
#define OFF_T3B 112416
#define WTOT    112418

__device__ __forceinline__ float bf2f(unsigned short u) {
    return __uint_as_float(((unsigned int)u) << 16);
}
__device__ __forceinline__ unsigned short f2bf(float f) {
    unsigned int u = __float_as_uint(f);
    u = (u + 0x7fffu + ((u >> 16) & 1u)) >> 16;
    return (unsigned short)u;
}
__device__ __forceinline__ float leakyf(float v) { return v >= 0.f ? v : 0.3f * v; }
__device__ __forceinline__ float tanh_fast(float v) {
    float e = __expf(2.f * v);
    return 1.f - 2.f / (e + 1.f);
}
__device__ __forceinline__ int rfl(int v) { return __builtin_amdgcn_readfirstlane(v); }

// ---------- dtype sniffer: 0 = bf16, 1 = f32 ----------
// Under bf16, every aligned short of h is a valid bf16 of N(0,1) (exp field in
// [100,132] essentially always). Under f32, even shorts are low mantissa halves
// (exp-field bits uniform -> ~13% in range).
__global__ void k_sniff(const unsigned short* __restrict__ hs, int* __restrict__ flag) {
    int lane = threadIdx.x;
    unsigned short s = hs[2 * lane];
    int ef = (s >> 7) & 0xFF;
    unsigned long long m = __ballot(ef >= 100 && ef <= 132);
    if (lane == 0) flag[0] = (__popcll(m) >= 40) ? 0 : 1;
}

// ---------- convert all weight tensors to one f32 table ----------
__global__ __launch_bounds__(1024) void k_convert(
    const int* __restrict__ fl,
    const void* t1w, const void* t1b,
    const void* gw1a, const void* gw1b, const void* gw1c,
    const void* gb1a, const void* gb1b, const void* gb1c,
    const void* hw1a, const void* hw1b, const void* hw1c,
    const void* gw2a, const void* gw2b, const void* gw2c,
    const void* gb2a, const void* gb2b, const void* gb2c,
    const void* hw2a, const void* hw2b, const void* hw2c,
    const void* t2w, const void* t2b, const void* t3w, const void* t3b,
    float* __restrict__ fw) {
    const int starts[24] = {0, 16384, 16448, 16576, 16704, 16832, 16833, 16834,
                            16848, 20944, 25040, 29136, 29520, 29904, 30288, 30289, 30290,
                            30304, 42592, 54880, 67168, 112224, 112288, 112416};
    const int cnts[24] = {16384, 64, 128, 128, 128, 1, 1, 1, 4096, 4096, 4096,
                          384, 384, 384, 1, 1, 1, 12288, 12288, 12288, 45056, 64, 128, 2};
    const void* sp[24] = {t1w, t1b, gw1a, gw1b, gw1c, gb1a, gb1b, gb1c, hw1a, hw1b, hw1c,
                          gw2a, gw2b, gw2c, gb2a, gb2b, gb2c, hw2a, hw2b, hw2c, t2w, t2b, t3w, t3b};
    int isf32 = fl[0];
    int idx = blockIdx.x * 1024 + threadIdx.x;
    if (idx >= WTOT) return;
    float v = 0.f;
#pragma unroll
    for (int k = 0; k < 24; ++k) {
        int lo = idx - starts[k];
        if (lo >= 0 && lo < cnts[k])
            v = isf32 ? ((const float*)sp[k])[lo] : bf2f(((const unsigned short*)sp[k])[lo]);
    }
    fw[idx] = v;
}

// ---------- degree count ----------
__global__ __launch_bounds__(256) void k_deg(const int* __restrict__ d0, const int* __restrict__ d1,
                                             const int* __restrict__ d2, int* __restrict__ deg) {
    int set = blockIdx.y;
    const int* dd = set == 0 ? d0 : (set == 1 ? d1 : d2);
    int t = blockIdx.x * 256 + threadIdx.x;
    if (t < EE) atomicAdd(&deg[(size_t)set * NN + dd[t]], 1);
}

// ---------- d = deg>0 ? rsqrt(deg) : 0, packed into .y of per-node float2s ----------
__global__ __launch_bounds__(256) void k_dnorm(const int* __restrict__ deg, float2* __restrict__ g1,
                                               float2* __restrict__ g2) {
    int t = blockIdx.x * 256 + threadIdx.x;
    if (t < 3 * NN) {
        int g = deg[t];
        float v = g > 0 ? rsqrtf((float)g) : 0.f;
        g1[t].y = v;
        g2[t].y = v;
    }
}

// ---------- hierarchical exclusive scan (1024 elems/block) ----------
__global__ __launch_bounds__(256) void k_scan1(const int* __restrict__ deg, int* __restrict__ rowptr,
                                               int* __restrict__ bsum) {
    int set = blockIdx.y;
    const int* dg = deg + (size_t)set * NN;
    int* rp = rowptr + (size_t)set * NN;
    __shared__ int sh[256];
    int tid = threadIdx.x;
    int base = blockIdx.x * 1024 + tid * 4;
    int v[4]; int s = 0;
#pragma unroll
    for (int c = 0; c < 4; ++c) { int idx = base + c; v[c] = (idx < NN) ? dg[idx] : 0; s += v[c]; }
    sh[tid] = s;
    __syncthreads();
    for (int off = 1; off < 256; off <<= 1) {
        int t = 0;
        if (tid >= off) t = sh[tid - off];
        __syncthreads();
        if (tid >= off) sh[tid] += t;
        __syncthreads();
    }
    int run = sh[tid] - s;
#pragma unroll
    for (int c = 0; c < 4; ++c) { int idx = base + c; if (idx < NN) rp[idx] = run; run += v[c]; }
    if (tid == 255) bsum[set * SCAN_BLK + blockIdx.x] = sh[255];
}

__global__ void k_scan2(int* __restrict__ bsum) {
    int set = blockIdx.x;
    int* b = bsum + set * SCAN_BLK;
    if (threadIdx.x == 0) {
        int acc = 0;
        for (int i = 0; i < SCAN_BLK; ++i) { int t = b[i]; b[i] = acc; acc += t; }
    }
}

__global__ __launch_bounds__(256) void k_scan3(int* __restrict__ rowptr, int* __restrict__ cursor,
                                               const int* __restrict__ bsum) {
    int set = blockIdx.y;
    int add = bsum[set * SCAN_BLK + blockIdx.x];
    int base = blockIdx.x * 1024 + threadIdx.x * 4;
    int* rp = rowptr + (size_t)set * NN;
    int* cur = cursor + (size_t)set * NN;
#pragma unroll
    for (int c = 0; c < 4; ++c) {
        int idx = base + c;
        if (idx < NN) { int vv = rp[idx] + add; rp[idx] = vv; cur[idx] = vv; }
    }
}

// ---------- scatter src ids into CSR-by-dst order ----------
__global__ __launch_bounds__(256) void k_scatter(const int* __restrict__ s0, const int* __restrict__ s1,
                                                 const int* __restrict__ s2, const int* __restrict__ d0,
                                                 const int* __restrict__ d1, const int* __restrict__ d2,
                                                 int* __restrict__ cursor, int* __restrict__ csr_src) {
    int set = blockIdx.y;
    const int* ss = set == 0 ? s0 : (set == 1 ? s1 : s2);
    const int* dd = set == 0 ? d0 : (set == 1 ? d1 : d2);
    int t = blockIdx.x * 256 + threadIdx.x;
    if (t >= EE) return;
    int dn_ = dd[t];
    int pos = atomicAdd(&cursor[(size_t)set * NN + dn_], 1);
    csr_src[(size_t)set * EE + pos] = ss[t];
}

// ---------- input transform: x = leaky(h @ t1w^T + b), plus layer-1 gate scalars ----------
__global__ __launch_bounds__(1024) void k_input(const int* __restrict__ fl,
                                                const void* __restrict__ hB,
                                                const float* __restrict__ fw,
                                                float* __restrict__ x, float* __restrict__ p1d,
                                                float2* __restrict__ g1v) {
    __shared__ float wT[128 * 65];
    __shared__ __align__(16) float hbuf[16][256];
    int tid = threadIdx.x, lane = tid & 63, wid = tid >> 6;
    int node = blockIdx.x * 16 + wid;
    int isf32 = fl[0];
    if (isf32) {
        float4 hv = ((const float4*)hB)[(size_t)node * 64 + lane];
        hbuf[wid][lane * 4 + 0] = hv.x;
        hbuf[wid][lane * 4 + 1] = hv.y;
        hbuf[wid][lane * 4 + 2] = hv.z;
        hbuf[wid][lane * 4 + 3] = hv.w;
    } else {
        ushort4 hv = ((const ushort4*)hB)[(size_t)node * 64 + lane];
        hbuf[wid][lane * 4 + 0] = bf2f(hv.x);
        hbuf[wid][lane * 4 + 1] = bf2f(hv.y);
        hbuf[wid][lane * 4 + 2] = bf2f(hv.z);
        hbuf[wid][lane * 4 + 3] = bf2f(hv.w);
    }
    float acc = fw[OFF_T1B + lane];
    for (int c = 0; c < 2; ++c) {
        __syncthreads();
        for (int idx = tid; idx < 64 * 128; idx += 1024) {
            int j = idx >> 7, kk = idx & 127;
            wT[kk * 65 + j] = fw[OFF_T1W + j * 256 + c * 128 + kk];
        }
        __syncthreads();
#pragma unroll 8
        for (int kk = 0; kk < 128; ++kk)
            acc = fmaf(hbuf[wid][c * 128 + kk], wT[kk * 65 + lane], acc);
    }
    float xv = leakyf(acc);
    x[(size_t)node * 64 + lane] = xv;
#pragma unroll
    for (int k = 0; k < 3; ++k) {
        float pd = xv * fw[OFF_GW1 + k * 128 + lane];
        float ps = xv * fw[OFF_GW1 + k * 128 + 64 + lane];
#pragma unroll
        for (int m = 32; m >= 1; m >>= 1) { pd += __shfl_xor(pd, m); ps += __shfl_xor(ps, m); }
        if (lane == 0) { p1d[(size_t)k * NN + node] = pd; g1v[(size_t)k * NN + node].x = ps; }
    }
}

// ---------- layer 1: inline gate + aggregate + 64x64 GEMV ----------
__global__ __launch_bounds__(1024) void k_layer1(const float* __restrict__ x,
                                                 const int* __restrict__ csr_src,
                                                 const int* __restrict__ rowptr,
                                                 const int* __restrict__ deg,
                                                 const float* __restrict__ p1d,
                                                 const float2* __restrict__ g1v,
                                                 const float* __restrict__ fw,
                                                 float* __restrict__ raw2) {
    int set = blockIdx.y;
    __shared__ float w[4096];
    __shared__ float tb[16][64];
    int tid = threadIdx.x, lane = tid & 63, wid = tid >> 6;
    for (int idx = tid; idx < 4096; idx += 1024) w[idx] = fw[OFF_HW1 + set * 4096 + idx];
    int node = blockIdx.x * 16 + wid;
    int start = rfl(rowptr[(size_t)set * NN + node]);
    int cnt = rfl(deg[(size_t)set * NN + node]);
    float pdv = p1d[(size_t)set * NN + node];
    float dnd = g1v[(size_t)set * NN + node].y;
    float gbv = fw[OFF_GB1 + set];
    const int* cs = csr_src + (size_t)set * EE + start;
    const float2* gv = g1v + (size_t)set * NN;
    float acc = 0.f;
    int s_nx = 0; float2 g_nx = make_float2(0.f, 0.f);
    if (cnt > 0) { s_nx = cs[0]; g_nx = gv[s_nx]; }
    for (int j = 0; j < cnt; ++j) {
        int s = s_nx; float2 g = g_nx;
        if (j + 1 < cnt) { s_nx = cs[j + 1]; g_nx = gv[s_nx]; }
        float a = tanh_fast(pdv + g.x + gbv);
        float e = a * dnd * g.y;
        acc = fmaf(x[(size_t)s * 64 + lane], e, acc);
    }
    float t = fmaf(0.3f, x[(size_t)node * 64 + lane], acc);  // EPS residual
    tb[wid][lane] = t;
    __syncthreads();
    float o = 0.f;
#pragma unroll 8
    for (int k = 0; k < 64; ++k) o = fmaf(tb[wid][k], w[k * 64 + lane], o);
    raw2[(size_t)node * 192 + set * 64 + lane] = leakyf(o);
}

// ---------- layer-2 gate scalars from raw2 ----------
__global__ __launch_bounds__(1024) void k_p2(const float* __restrict__ raw2,
                                             const float* __restrict__ fw,
                                             float* __restrict__ p2d, float2* __restrict__ g2v) {
    int tid = threadIdx.x, lane = tid & 63, wid = tid >> 6;
    int node = blockIdx.x * 16 + wid;
    float v0 = raw2[(size_t)node * 192 + lane];
    float v1 = raw2[(size_t)node * 192 + 64 + lane];
    float v2 = raw2[(size_t)node * 192 + 128 + lane];
#pragma unroll
    for (int k = 0; k < 3; ++k) {
        const float* g = fw + OFF_GW2 + k * 384;
        float pd = v0 * g[lane] + v1 * g[64 + lane] + v2 * g[128 + lane];
        float ps = v0 * g[192 + lane] + v1 * g[256 + lane] + v2 * g[320 + lane];
#pragma unroll
        for (int m = 32; m >= 1; m >>= 1) { pd += __shfl_xor(pd, m); ps += __shfl_xor(ps, m); }
        if (lane == 0) { p2d[(size_t)k * NN + node] = pd; g2v[(size_t)k * NN + node].x = ps; }
    }
}

// ---------- mark batch nodes, assign compact slots ----------
__global__ __launch_bounds__(256) void k_mark(const int* __restrict__ nodes, int* __restrict__ mark,
                                              int* __restrict__ slotof, int* __restrict__ cnt) {
    int b = blockIdx.x * 256 + threadIdx.x;
    if (b < BB) {
        int n = nodes[b];
        if (atomicCAS(&mark[n], 0, 1) == 0) {
            int s = atomicAdd(cnt, 1);
            slotof[n] = s;
        }
    }
}

// ---------- layer 2 aggregation (marked dst only), inline gate ----------
__global__ __launch_bounds__(1024) void k_layer2(const float* __restrict__ raw2,
                                                 const int* __restrict__ csr_src,
                                                 const int* __restrict__ rowptr,
                                                 const int* __restrict__ deg,
                                                 const float* __restrict__ p2d,
                                                 const float2* __restrict__ g2v,
                                                 const float* __restrict__ fw,
                                                 const int* __restrict__ mark,
                                                 const int* __restrict__ slotof,
                                                 float* __restrict__ z2) {
    int set = blockIdx.y;
    int tid = threadIdx.x, lane = tid & 63, wid = tid >> 6;
    int node = blockIdx.x * 16 + wid;
    if (mark[node] == 0) return;
    int start = rfl(rowptr[(size_t)set * NN + node]);
    int cnt = rfl(deg[(size_t)set * NN + node]);
    float pdv = p2d[(size_t)set * NN + node];
    float dnd = g2v[(size_t)set * NN + node].y;
    float gbv = fw[OFF_GB2 + set];
    const int* cs = csr_src + (size_t)set * EE + start;
    const float2* gv = g2v + (size_t)set * NN;
    float a0 = 0.f, a1 = 0.f, a2 = 0.f;
    int s_nx = 0; float2 g_nx = make_float2(0.f, 0.f);
    if (cnt > 0) { s_nx = cs[0]; g_nx = gv[s_nx]; }
    for (int j = 0; j < cnt; ++j) {
        int s = s_nx; float2 g = g_nx;
        if (j + 1 < cnt) { s_nx = cs[j + 1]; g_nx = gv[s_nx]; }
        float a = tanh_fast(pdv + g.x + gbv);
        float e = a * dnd * g.y;
        const float* r = raw2 + (size_t)s * 192;
        a0 = fmaf(r[lane], e, a0);
        a1 = fmaf(r[64 + lane], e, a1);
        a2 = fmaf(r[128 + lane], e, a2);
    }
    float* z = z2 + (size_t)slotof[node] * 576 + (size_t)set * 192;
    z[lane] = a0; z[64 + lane] = a1; z[128 + lane] = a2;
}

// ---------- final: h2 GEMVs + 704->64->2 MLP per batch row ----------
__global__ __launch_bounds__(256) void k_final(const int* __restrict__ fl,
                                               const int* __restrict__ nodes,
                                               const int* __restrict__ slotof,
                                               const float* __restrict__ z2,
                                               const float* __restrict__ raw2,
                                               const float* __restrict__ x,
                                               const void* __restrict__ hB,
                                               const float* __restrict__ fw,
                                               void* __restrict__ outv) {
    __shared__ float wbuf[192 * 64];   // 48 KB, reused: hw2 stage then t2w chunks [<=128][65]
    __shared__ float nf[4][704];
    __shared__ float tb[4][192];
    int tid = threadIdx.x, lane = tid & 63, wid = tid >> 6;
    int b = blockIdx.x * 4 + wid;
    int node = nodes[b];
    int slot = slotof[node];
    int isf32 = fl[0];
    float r2[3];
#pragma unroll
    for (int r = 0; r < 4; ++r) {
        size_t hi = (size_t)node * 256 + r * 64 + lane;
        nf[wid][192 + r * 64 + lane] = isf32 ? ((const float*)hB)[hi]
                                             : bf2f(((const unsigned short*)hB)[hi]);
    }
    nf[wid][448 + lane] = x[(size_t)node * 64 + lane];
#pragma unroll
    for (int r = 0; r < 3; ++r) {
        r2[r] = raw2[(size_t)node * 192 + r * 64 + lane];
        nf[wid][512 + r * 64 + lane] = r2[r];
    }
    for (int set = 0; set < 3; ++set) {
        __syncthreads();
        for (int idx = tid; idx < 192 * 64; idx += 256) wbuf[idx] = fw[OFF_HW2 + set * 12288 + idx];
#pragma unroll
        for (int r = 0; r < 3; ++r)
            tb[wid][r * 64 + lane] = fmaf(0.3f, r2[r], z2[(size_t)slot * 576 + set * 192 + r * 64 + lane]);
        __syncthreads();
        float o = 0.f;
#pragma unroll 8
        for (int k = 0; k < 192; ++k) o = fmaf(tb[wid][k], wbuf[k * 64 + lane], o);
        nf[wid][set * 64 + lane] = leakyf(o);
    }
    float acc = fw[OFF_T2B + lane];
#pragma unroll
    for (int c = 0; c < 6; ++c) {
        int k0 = c * 128;
        int kw = (c == 5) ? 64 : 128;
        __syncthreads();
        for (int idx = tid; idx < 64 * kw; idx += 256) {
            int j = idx / kw, kk = idx % kw;
            wbuf[kk * 65 + j] = fw[OFF_T2W + j * 704 + k0 + kk];
        }
        __syncthreads();
        for (int kk = 0; kk < kw; ++kk) acc = fmaf(nf[wid][k0 + kk], wbuf[kk * 65 + lane], acc);
    }
    float sv = leakyf(acc);
    float r0 = sv * fw[OFF_T3W + lane];
    float r1 = sv * fw[OFF_T3W + 64 + lane];
#pragma unroll
    for (int m = 32; m >= 1; m >>= 1) { r0 += __shfl_xor(r0, m); r1 += __shfl_xor(r1, m); }
    if (isf32) {
        float* out = (float*)outv;
        out[8192 + (size_t)b * 64 + lane] = sv;
        if (lane == 0) {
            out[(size_t)b * 2 + 0] = r0 + fw[OFF_T3B + 0];
            out[(size_t)b * 2 + 1] = r1 + fw[OFF_T3B + 1];
        }
    } else {
        unsigned short* out = (unsigned short*)outv;
        out[8192 + (size_t)b * 64 + lane] = f2bf(sv);
        if (lane == 0) {
            out[(size_t)b * 2 + 0] = f2bf(r0 + fw[OFF_T3B + 0]);
            out[(size_t)b * 2 + 1] = f2bf(r1 + fw[OFF_T3B + 1]);
        }
    }
}

extern "C" void kernel_launch(void* const* d_in, const int* in_sizes, int n_in,
                              void* d_out, int out_size, void* d_ws, size_t ws_size,
                              hipStream_t stream) {
    const void* h = d_in[0];
    const int* src1 = (const int*)d_in[1];
    const int* dst1 = (const int*)d_in[2];
    const int* src2 = (const int*)d_in[3];
    const int* dst2 = (const int*)d_in[4];
    const int* src3 = (const int*)d_in[5];
    const int* dst3 = (const int*)d_in[6];
    const int* nodes = (const int*)d_in[7];

    char* w = (char*)d_ws;
    size_t off = 0;
    auto carve = [&](size_t bytes) -> void* {
        void* p = w + off;
        off += (bytes + 255) & ~(size_t)255;
        return p;
    };
    int* flag = (int*)carve(256);
    int* deg = (int*)carve((size_t)3 * NN * 4);
    int* rowptr = (int*)carve((size_t)3 * NN * 4);
    int* cursor = (int*)carve((size_t)3 * NN * 4);
    int* bsum = (int*)carve((size_t)3 * 64 * 4);
    float2* g1v = (float2*)carve((size_t)3 * NN * 8);
    float2* g2v = (float2*)carve((size_t)3 * NN * 8);
    int* csr_src = (int*)carve((size_t)3 * EE * 4);
    float* fw = (float*)carve((size_t)WTOT * 4);
    float* x = (float*)carve((size_t)NN * 64 * 4);
    float* p1d = (float*)carve((size_t)3 * NN * 4);
    float* p2d = (float*)carve((size_t)3 * NN * 4);
    float* raw2 = (float*)carve((size_t)NN * 192 * 4);
    int* mark = (int*)carve((size_t)NN * 4);
    int* slotof = (int*)carve((size_t)NN * 4);
    int* cntp = (int*)carve(256);
    float* z2 = (float*)carve((size_t)BB * 576 * 4);

    hipMemsetAsync(deg, 0, (size_t)3 * NN * 4, stream);
    hipMemsetAsync(mark, 0, (size_t)NN * 4, stream);
    hipMemsetAsync(cntp, 0, 4, stream);

    k_sniff<<<1, 64, 0, stream>>>((const unsigned short*)h, flag);
    k_convert<<<(WTOT + 1023) / 1024, 1024, 0, stream>>>(
        flag, d_in[8], d_in[9],
        d_in[10], d_in[16], d_in[22],     // gw1_1..3
        d_in[11], d_in[17], d_in[23],     // gb1_1..3
        d_in[12], d_in[18], d_in[24],     // hw1_1..3
        d_in[13], d_in[19], d_in[25],     // gw2_1..3
        d_in[14], d_in[20], d_in[26],     // gb2_1..3
        d_in[15], d_in[21], d_in[27],     // hw2_1..3
        d_in[28], d_in[29], d_in[30], d_in[31], fw);

    dim3 ge(3125, 3);
    k_deg<<<ge, 256, 0, stream>>>(dst1, dst2, dst3, deg);
    k_dnorm<<<(3 * NN + 255) / 256, 256, 0, stream>>>(deg, g1v, g2v);
    dim3 gsc(SCAN_BLK, 3);
    k_scan1<<<gsc, 256, 0, stream>>>(deg, rowptr, bsum);
    k_scan2<<<3, 64, 0, stream>>>(bsum);
    k_scan3<<<gsc, 256, 0, stream>>>(rowptr, cursor, bsum);
    k_scatter<<<ge, 256, 0, stream>>>(src1, src2, src3, dst1, dst2, dst3, cursor, csr_src);

    k_input<<<3125, 1024, 0, stream>>>(flag, h, fw, x, p1d, g1v);
    dim3 gl(3125, 3);
    k_layer1<<<gl, 1024, 0, stream>>>(x, csr_src, rowptr, deg, p1d, g1v, fw, raw2);
    k_p2<<<3125, 1024, 0, stream>>>(raw2, fw, p2d, g2v);
    k_mark<<<(BB + 255) / 256, 256, 0, stream>>>(nodes, mark, slotof, cntp);
    k_layer2<<<gl, 1024, 0, stream>>>(raw2, csr_src, rowptr, deg, p2d, g2v, fw, mark, slotof, z2);
    k_final<<<BB / 4, 256, 0, stream>>>(flag, nodes, slotof, z2, raw2, x, h, fw, d_out);
}

// Round 3
// 633.787 us; speedup vs baseline: 1.4203x; 1.4203x over previous
//
#include <hip/hip_runtime.h>

#define NN 50000
#define EE 800000
#define BB 4096
#define SCAN_BLK 49   // ceil(50000/1024)

// f32 weight-table offsets (elements)
#define OFF_T1W 0
#define OFF_T1B 16384
#define OFF_GW1 16448
#define OFF_GB1 16832
#define OFF_HW1 16848
#define OFF_GW2 29136
#define OFF_GB2 30288
#define OFF_HW2 30304
#define OFF_T2W 67168
#define OFF_T2B 112224
#define OFF_T3W 112288
#define OFF_T3B 112416
#define WTOT    112418

// bf16 weight table (for MFMA B-operands)
#define WB_T1W  0        // t1w native [64][256]
#define WB_HW1T 16384    // 3 x hw1^T [64][64]
#define WB_TOT  28672

typedef __attribute__((ext_vector_type(8))) short bf16x8;
typedef __attribute__((ext_vector_type(4))) float f32x4;

__device__ __forceinline__ float bf2f(unsigned short u) {
    return __uint_as_float(((unsigned int)u) << 16);
}
__device__ __forceinline__ unsigned short f2bf(float f) {
    unsigned int u = __float_as_uint(f);
    u = (u + 0x7fffu + ((u >> 16) & 1u)) >> 16;
    return (unsigned short)u;
}
__device__ __forceinline__ float leakyf(float v) { return v >= 0.f ? v : 0.3f * v; }
__device__ __forceinline__ float tanh_fast(float v) {
    float e = __expf(2.f * v);
    return 1.f - 2.f / (e + 1.f);
}
__device__ __forceinline__ int rfl(int v) { return __builtin_amdgcn_readfirstlane(v); }

// ---------- dtype sniffer: 0 = bf16, 1 = f32 ----------
__global__ void k_sniff(const unsigned short* __restrict__ hs, int* __restrict__ flag) {
    int lane = threadIdx.x;
    unsigned short s = hs[2 * lane];
    int ef = (s >> 7) & 0xFF;
    unsigned long long m = __ballot(ef >= 100 && ef <= 132);
    if (lane == 0) flag[0] = (__popcll(m) >= 40) ? 0 : 1;
}

// ---------- convert all weight tensors to one f32 table ----------
__global__ __launch_bounds__(1024) void k_convert(
    const int* __restrict__ fl,
    const void* t1w, const void* t1b,
    const void* gw1a, const void* gw1b, const void* gw1c,
    const void* gb1a, const void* gb1b, const void* gb1c,
    const void* hw1a, const void* hw1b, const void* hw1c,
    const void* gw2a, const void* gw2b, const void* gw2c,
    const void* gb2a, const void* gb2b, const void* gb2c,
    const void* hw2a, const void* hw2b, const void* hw2c,
    const void* t2w, const void* t2b, const void* t3w, const void* t3b,
    float* __restrict__ fw) {
    const int starts[24] = {0, 16384, 16448, 16576, 16704, 16832, 16833, 16834,
                            16848, 20944, 25040, 29136, 29520, 29904, 30288, 30289, 30290,
                            30304, 42592, 54880, 67168, 112224, 112288, 112416};
    const int cnts[24] = {16384, 64, 128, 128, 128, 1, 1, 1, 4096, 4096, 4096,
                          384, 384, 384, 1, 1, 1, 12288, 12288, 12288, 45056, 64, 128, 2};
    const void* sp[24] = {t1w, t1b, gw1a, gw1b, gw1c, gb1a, gb1b, gb1c, hw1a, hw1b, hw1c,
                          gw2a, gw2b, gw2c, gb2a, gb2b, gb2c, hw2a, hw2b, hw2c, t2w, t2b, t3w, t3b};
    int isf32 = fl[0];
    int idx = blockIdx.x * 1024 + threadIdx.x;
    if (idx >= WTOT) return;
    float v = 0.f;
#pragma unroll
    for (int k = 0; k < 24; ++k) {
        int lo = idx - starts[k];
        if (lo >= 0 && lo < cnts[k])
            v = isf32 ? ((const float*)sp[k])[lo] : bf2f(((const unsigned short*)sp[k])[lo]);
    }
    fw[idx] = v;
}

// ---------- bf16 weight table: t1w native + hw1 transposed ----------
__global__ __launch_bounds__(256) void k_convert16(const int* __restrict__ fl, const void* t1w,
                                                   const void* hw1a, const void* hw1b,
                                                   const void* hw1c, unsigned short* __restrict__ wb) {
    int idx = blockIdx.x * 256 + threadIdx.x;
    if (idx >= WB_TOT) return;
    int isf32 = fl[0];
    unsigned short v;
    if (idx < 16384) {
        v = isf32 ? f2bf(((const float*)t1w)[idx]) : ((const unsigned short*)t1w)[idx];
    } else {
        int rel = idx - 16384;
        int set = rel >> 12, r2 = rel & 4095;
        int jj = r2 >> 6, kk = r2 & 63;
        const void* p = set == 0 ? hw1a : (set == 1 ? hw1b : hw1c);
        int srci = kk * 64 + jj;   // hw1T[j][k] = hw1[k][j]
        v = isf32 ? f2bf(((const float*)p)[srci]) : ((const unsigned short*)p)[srci];
    }
    wb[idx] = v;
}

// ---------- degree count ----------
__global__ __launch_bounds__(256) void k_deg(const int* __restrict__ d0, const int* __restrict__ d1,
                                             const int* __restrict__ d2, int* __restrict__ deg) {
    int set = blockIdx.y;
    const int* dd = set == 0 ? d0 : (set == 1 ? d1 : d2);
    int t = blockIdx.x * 256 + threadIdx.x;
    if (t < EE) atomicAdd(&deg[(size_t)set * NN + dd[t]], 1);
}

// ---------- d into .z of per-node float4 packs (x=ps, y=pd, z=d) ----------
__global__ __launch_bounds__(256) void k_dnorm(const int* __restrict__ deg, float* __restrict__ g1,
                                               float* __restrict__ g2) {
    int t = blockIdx.x * 256 + threadIdx.x;
    if (t < 3 * NN) {
        int g = deg[t];
        float v = g > 0 ? rsqrtf((float)g) : 0.f;
        g1[(size_t)t * 4 + 2] = v;
        g2[(size_t)t * 4 + 2] = v;
    }
}

// ---------- hierarchical exclusive scan ----------
__global__ __launch_bounds__(256) void k_scan1(const int* __restrict__ deg, int* __restrict__ rowptr,
                                               int* __restrict__ bsum) {
    int set = blockIdx.y;
    const int* dg = deg + (size_t)set * NN;
    int* rp = rowptr + (size_t)set * NN;
    __shared__ int sh[256];
    int tid = threadIdx.x;
    int base = blockIdx.x * 1024 + tid * 4;
    int v[4]; int s = 0;
#pragma unroll
    for (int c = 0; c < 4; ++c) { int idx = base + c; v[c] = (idx < NN) ? dg[idx] : 0; s += v[c]; }
    sh[tid] = s;
    __syncthreads();
    for (int off = 1; off < 256; off <<= 1) {
        int t = 0;
        if (tid >= off) t = sh[tid - off];
        __syncthreads();
        if (tid >= off) sh[tid] += t;
        __syncthreads();
    }
    int run = sh[tid] - s;
#pragma unroll
    for (int c = 0; c < 4; ++c) { int idx = base + c; if (idx < NN) rp[idx] = run; run += v[c]; }
    if (tid == 255) bsum[set * SCAN_BLK + blockIdx.x] = sh[255];
}

__global__ void k_scan2(int* __restrict__ bsum) {
    int set = blockIdx.x;
    int* b = bsum + set * SCAN_BLK;
    if (threadIdx.x == 0) {
        int acc = 0;
        for (int i = 0; i < SCAN_BLK; ++i) { int t = b[i]; b[i] = acc; acc += t; }
    }
}

__global__ __launch_bounds__(256) void k_scan3(int* __restrict__ rowptr, int* __restrict__ cursor,
                                               const int* __restrict__ bsum) {
    int set = blockIdx.y;
    int add = bsum[set * SCAN_BLK + blockIdx.x];
    int base = blockIdx.x * 1024 + threadIdx.x * 4;
    int* rp = rowptr + (size_t)set * NN;
    int* cur = cursor + (size_t)set * NN;
#pragma unroll
    for (int c = 0; c < 4; ++c) {
        int idx = base + c;
        if (idx < NN) { int vv = rp[idx] + add; rp[idx] = vv; cur[idx] = vv; }
    }
}

// ---------- input transform via MFMA: x = leaky(h @ t1w^T + b), fused p1 gate dots ----------
__global__ __launch_bounds__(256) void k_input(const int* __restrict__ fl,
                                               const void* __restrict__ hB,
                                               const unsigned short* __restrict__ wb,
                                               const float* __restrict__ fw,
                                               unsigned short* __restrict__ x16,
                                               float4* __restrict__ g1v4) {
    __shared__ float xt[16][65];
    int tid = threadIdx.x, lane = tid & 63, wid = tid >> 6;
    int m = lane & 15, q = lane >> 4;
    int node0 = blockIdx.x * 16;
    int isf32 = fl[0];
    f32x4 acc = {0.f, 0.f, 0.f, 0.f};
    const unsigned short* bsrc = wb + WB_T1W + ((size_t)(wid * 16 + m)) * 256 + q * 8;
    if (isf32) {
        const float* ap = (const float*)hB + (size_t)(node0 + m) * 256 + q * 8;
        for (int k0 = 0; k0 < 256; k0 += 32) {
            float4 f0 = *(const float4*)(ap + k0);
            float4 f1 = *(const float4*)(ap + k0 + 4);
            bf16x8 a;
            a[0] = (short)f2bf(f0.x); a[1] = (short)f2bf(f0.y);
            a[2] = (short)f2bf(f0.z); a[3] = (short)f2bf(f0.w);
            a[4] = (short)f2bf(f1.x); a[5] = (short)f2bf(f1.y);
            a[6] = (short)f2bf(f1.z); a[7] = (short)f2bf(f1.w);
            bf16x8 b = *(const bf16x8*)(bsrc + k0);
            acc = __builtin_amdgcn_mfma_f32_16x16x32_bf16(a, b, acc, 0, 0, 0);
        }
    } else {
        const unsigned short* ap = (const unsigned short*)hB + (size_t)(node0 + m) * 256 + q * 8;
        for (int k0 = 0; k0 < 256; k0 += 32) {
            bf16x8 a = *(const bf16x8*)(ap + k0);
            bf16x8 b = *(const bf16x8*)(bsrc + k0);
            acc = __builtin_amdgcn_mfma_f32_16x16x32_bf16(a, b, acc, 0, 0, 0);
        }
    }
    int gcol = wid * 16 + m;
    float bias = fw[OFF_T1B + gcol];
#pragma unroll
    for (int r = 0; r < 4; ++r) {
        int row = q * 4 + r;
        float v = leakyf(acc[r] + bias);
        x16[(size_t)(node0 + row) * 64 + gcol] = f2bf(v);
        xt[row][gcol] = v;
    }
    __syncthreads();
    // p1 gate dots: wave wid handles nodes wid*4 + q; 16 lanes per node cover 64 cols
    int nl = wid * 4 + q;
    int node = node0 + nl;
    float xv[4];
#pragma unroll
    for (int r = 0; r < 4; ++r) xv[r] = xt[nl][m + 16 * r];
#pragma unroll
    for (int set = 0; set < 3; ++set) {
        const float* gw = fw + OFF_GW1 + set * 128;
        float pd = 0.f, ps = 0.f;
#pragma unroll
        for (int r = 0; r < 4; ++r) {
            int c = m + 16 * r;
            pd = fmaf(xv[r], gw[c], pd);
            ps = fmaf(xv[r], gw[64 + c], ps);
        }
        pd += __shfl_xor(pd, 1); ps += __shfl_xor(ps, 1);
        pd += __shfl_xor(pd, 2); ps += __shfl_xor(ps, 2);
        pd += __shfl_xor(pd, 4); ps += __shfl_xor(ps, 4);
        pd += __shfl_xor(pd, 8); ps += __shfl_xor(ps, 8);
        if (m == 0) {
            float2* p = (float2*)&g1v4[(size_t)set * NN + node];
            *p = make_float2(ps, pd);   // .x=ps, .y=pd
        }
    }
}

// ---------- scatter edges into CSR order, fused layer-1 gate coefficient ----------
__global__ __launch_bounds__(256) void k_scatter(const int* __restrict__ s0, const int* __restrict__ s1,
                                                 const int* __restrict__ s2, const int* __restrict__ d0,
                                                 const int* __restrict__ d1, const int* __restrict__ d2,
                                                 int* __restrict__ cursor,
                                                 const float4* __restrict__ g1v4,
                                                 const float* __restrict__ fw,
                                                 int2* __restrict__ csr_se) {
    int set = blockIdx.y;
    const int* ss = set == 0 ? s0 : (set == 1 ? s1 : s2);
    const int* dd = set == 0 ? d0 : (set == 1 ? d1 : d2);
    int t = blockIdx.x * 256 + threadIdx.x;
    if (t >= EE) return;
    int dn_ = dd[t];
    int s_ = ss[t];
    int pos = atomicAdd(&cursor[(size_t)set * NN + dn_], 1);
    float4 gd = g1v4[(size_t)set * NN + dn_];
    float4 gs = g1v4[(size_t)set * NN + s_];
    float a = tanh_fast(gd.y + gs.x + fw[OFF_GB1 + set]);
    float e = a * gd.z * gs.z;
    csr_se[(size_t)set * EE + pos] = make_int2(s_, __float_as_int(e));
}

// ---------- layer 1: aggregate (precomputed e) + MFMA 64x64 GEMV epilogue ----------
__global__ __launch_bounds__(1024) void k_layer1(const unsigned short* __restrict__ x16,
                                                 const int2* __restrict__ csr_se,
                                                 const int* __restrict__ rowptr,
                                                 const int* __restrict__ deg,
                                                 const unsigned short* __restrict__ wb,
                                                 unsigned short* __restrict__ raw2_16) {
    int set = blockIdx.y;
    __shared__ unsigned short tb[16][72];   // row stride 144 B -> 16B-aligned bf16x8 loads
    int tid = threadIdx.x, lane = tid & 63, wid = tid >> 6;
    int m = lane & 15, q = lane >> 4;
    int node = blockIdx.x * 16 + wid;
    int start = rfl(rowptr[(size_t)set * NN + node]);
    int cnt = rfl(deg[(size_t)set * NN + node]);
    const int2* cs = csr_se + (size_t)set * EE + start;
    float acc = 0.f;
    int j = 0;
    for (; j + 4 <= cnt; j += 4) {
        int2 e0 = cs[j], e1 = cs[j + 1], e2 = cs[j + 2], e3 = cs[j + 3];
        float v0 = bf2f(x16[(size_t)e0.x * 64 + lane]);
        float v1 = bf2f(x16[(size_t)e1.x * 64 + lane]);
        float v2 = bf2f(x16[(size_t)e2.x * 64 + lane]);
        float v3 = bf2f(x16[(size_t)e3.x * 64 + lane]);
        acc = fmaf(v0, __int_as_float(e0.y), acc);
        acc = fmaf(v1, __int_as_float(e1.y), acc);
        acc = fmaf(v2, __int_as_float(e2.y), acc);
        acc = fmaf(v3, __int_as_float(e3.y), acc);
    }
    for (; j < cnt; ++j) {
        int2 e = cs[j];
        acc = fmaf(bf2f(x16[(size_t)e.x * 64 + lane]), __int_as_float(e.y), acc);
    }
    float t = fmaf(0.3f, bf2f(x16[(size_t)node * 64 + lane]), acc);  // EPS residual
    tb[wid][lane] = f2bf(t);
    __syncthreads();
    if (wid < 4) {
        f32x4 c = {0.f, 0.f, 0.f, 0.f};
        const unsigned short* bp = wb + WB_HW1T + set * 4096 + (wid * 16 + m) * 64 + q * 8;
#pragma unroll
        for (int k0 = 0; k0 < 64; k0 += 32) {
            bf16x8 a = *(const bf16x8*)&tb[m][k0 + q * 8];
            bf16x8 b = *(const bf16x8*)(bp + k0);
            c = __builtin_amdgcn_mfma_f32_16x16x32_bf16(a, b, c, 0, 0, 0);
        }
        int gcol = wid * 16 + m;
#pragma unroll
        for (int r = 0; r < 4; ++r) {
            int row = q * 4 + r;
            raw2_16[(size_t)(blockIdx.x * 16 + row) * 192 + set * 64 + gcol] = f2bf(leakyf(c[r]));
        }
    }
}

// ---------- layer-2 gate scalars from raw2 ----------
__global__ __launch_bounds__(1024) void k_p2(const unsigned short* __restrict__ raw2_16,
                                             const float* __restrict__ fw,
                                             float4* __restrict__ g2v4) {
    int tid = threadIdx.x, lane = tid & 63, wid = tid >> 6;
    int node = blockIdx.x * 16 + wid;
    const unsigned short* r = raw2_16 + (size_t)node * 192;
    float v0 = bf2f(r[lane]);
    float v1 = bf2f(r[64 + lane]);
    float v2 = bf2f(r[128 + lane]);
#pragma unroll
    for (int k = 0; k < 3; ++k) {
        const float* g = fw + OFF_GW2 + k * 384;
        float pd = v0 * g[lane] + v1 * g[64 + lane] + v2 * g[128 + lane];
        float ps = v0 * g[192 + lane] + v1 * g[256 + lane] + v2 * g[320 + lane];
#pragma unroll
        for (int mm = 32; mm >= 1; mm >>= 1) { pd += __shfl_xor(pd, mm); ps += __shfl_xor(ps, mm); }
        if (lane == 0) {
            float2* p = (float2*)&g2v4[(size_t)k * NN + node];
            *p = make_float2(ps, pd);
        }
    }
}

// ---------- mark batch nodes, assign compact slots ----------
__global__ __launch_bounds__(256) void k_mark(const int* __restrict__ nodes, int* __restrict__ mark,
                                              int* __restrict__ slotof, int* __restrict__ cnt) {
    int b = blockIdx.x * 256 + threadIdx.x;
    if (b < BB) {
        int n = nodes[b];
        if (atomicCAS(&mark[n], 0, 1) == 0) {
            int s = atomicAdd(cnt, 1);
            slotof[n] = s;
        }
    }
}

// ---------- layer 2 aggregation (marked dst only), inline gate ----------
__global__ __launch_bounds__(1024) void k_layer2(const unsigned short* __restrict__ raw2_16,
                                                 const int2* __restrict__ csr_se,
                                                 const int* __restrict__ rowptr,
                                                 const int* __restrict__ deg,
                                                 const float4* __restrict__ g2v4,
                                                 const float* __restrict__ fw,
                                                 const int* __restrict__ mark,
                                                 const int* __restrict__ slotof,
                                                 float* __restrict__ z2) {
    int set = blockIdx.y;
    int tid = threadIdx.x, lane = tid & 63, wid = tid >> 6;
    int node = blockIdx.x * 16 + wid;
    if (mark[node] == 0) return;
    int start = rfl(rowptr[(size_t)set * NN + node]);
    int cnt = rfl(deg[(size_t)set * NN + node]);
    float4 gn = g2v4[(size_t)set * NN + node];
    float pdv = gn.y, dnd = gn.z;
    float gbv = fw[OFF_GB2 + set];
    const int2* cs = csr_se + (size_t)set * EE + start;
    const float4* gv = g2v4 + (size_t)set * NN;
    float a0 = 0.f, a1 = 0.f, a2 = 0.f;
    for (int j = 0; j < cnt; ++j) {
        int2 se = cs[j];
        int s = se.x;
        float4 g = gv[s];
        float a = tanh_fast(pdv + g.x + gbv);
        float e = a * dnd * g.z;
        const unsigned short* r = raw2_16 + (size_t)s * 192;
        a0 = fmaf(bf2f(r[lane]), e, a0);
        a1 = fmaf(bf2f(r[64 + lane]), e, a1);
        a2 = fmaf(bf2f(r[128 + lane]), e, a2);
    }
    float* z = z2 + (size_t)slotof[node] * 576 + (size_t)set * 192;
    z[lane] = a0; z[64 + lane] = a1; z[128 + lane] = a2;
}

// ---------- final: h2 GEMVs + 704->64->2 MLP per batch row ----------
__global__ __launch_bounds__(256) void k_final(const int* __restrict__ fl,
                                               const int* __restrict__ nodes,
                                               const int* __restrict__ slotof,
                                               const float* __restrict__ z2,
                                               const unsigned short* __restrict__ raw2_16,
                                               const unsigned short* __restrict__ x16,
                                               const void* __restrict__ hB,
                                               const float* __restrict__ fw,
                                               void* __restrict__ outv) {
    __shared__ float wbuf[192 * 64];
    __shared__ float nf[4][704];
    __shared__ float tb[4][192];
    int tid = threadIdx.x, lane = tid & 63, wid = tid >> 6;
    int b = blockIdx.x * 4 + wid;
    int node = nodes[b];
    int slot = slotof[node];
    int isf32 = fl[0];
    float r2[3];
#pragma unroll
    for (int r = 0; r < 4; ++r) {
        size_t hi = (size_t)node * 256 + r * 64 + lane;
        nf[wid][192 + r * 64 + lane] = isf32 ? ((const float*)hB)[hi]
                                             : bf2f(((const unsigned short*)hB)[hi]);
    }
    nf[wid][448 + lane] = bf2f(x16[(size_t)node * 64 + lane]);
#pragma unroll
    for (int r = 0; r < 3; ++r) {
        r2[r] = bf2f(raw2_16[(size_t)node * 192 + r * 64 + lane]);
        nf[wid][512 + r * 64 + lane] = r2[r];
    }
    for (int set = 0; set < 3; ++set) {
        __syncthreads();
        for (int idx = tid; idx < 192 * 64; idx += 256) wbuf[idx] = fw[OFF_HW2 + set * 12288 + idx];
#pragma unroll
        for (int r = 0; r < 3; ++r)
            tb[wid][r * 64 + lane] = fmaf(0.3f, r2[r], z2[(size_t)slot * 576 + set * 192 + r * 64 + lane]);
        __syncthreads();
        float o = 0.f;
#pragma unroll 8
        for (int k = 0; k < 192; ++k) o = fmaf(tb[wid][k], wbuf[k * 64 + lane], o);
        nf[wid][set * 64 + lane] = leakyf(o);
    }
    float acc = fw[OFF_T2B + lane];
#pragma unroll
    for (int c = 0; c < 6; ++c) {
        int k0 = c * 128;
        int kw = (c == 5) ? 64 : 128;
        __syncthreads();
        for (int idx = tid; idx < 64 * kw; idx += 256) {
            int j = idx / kw, kk = idx % kw;
            wbuf[kk * 65 + j] = fw[OFF_T2W + j * 704 + k0 + kk];
        }
        __syncthreads();
        for (int kk = 0; kk < kw; ++kk) acc = fmaf(nf[wid][k0 + kk], wbuf[kk * 65 + lane], acc);
    }
    float sv = leakyf(acc);
    float r0 = sv * fw[OFF_T3W + lane];
    float r1 = sv * fw[OFF_T3W + 64 + lane];
#pragma unroll
    for (int mm = 32; mm >= 1; mm >>= 1) { r0 += __shfl_xor(r0, mm); r1 += __shfl_xor(r1, mm); }
    if (isf32) {
        float* out = (float*)outv;
        out[8192 + (size_t)b * 64 + lane] = sv;
        if (lane == 0) {
            out[(size_t)b * 2 + 0] = r0 + fw[OFF_T3B + 0];
            out[(size_t)b * 2 + 1] = r1 + fw[OFF_T3B + 1];
        }
    } else {
        unsigned short* out = (unsigned short*)outv;
        out[8192 + (size_t)b * 64 + lane] = f2bf(sv);
        if (lane == 0) {
            out[(size_t)b * 2 + 0] = f2bf(r0 + fw[OFF_T3B + 0]);
            out[(size_t)b * 2 + 1] = f2bf(r1 + fw[OFF_T3B + 1]);
        }
    }
}

extern "C" void kernel_launch(void* const* d_in, const int* in_sizes, int n_in,
                              void* d_out, int out_size, void* d_ws, size_t ws_size,
                              hipStream_t stream) {
    const void* h = d_in[0];
    const int* src1 = (const int*)d_in[1];
    const int* dst1 = (const int*)d_in[2];
    const int* src2 = (const int*)d_in[3];
    const int* dst2 = (const int*)d_in[4];
    const int* src3 = (const int*)d_in[5];
    const int* dst3 = (const int*)d_in[6];
    const int* nodes = (const int*)d_in[7];

    char* w = (char*)d_ws;
    size_t off = 0;
    auto carve = [&](size_t bytes) -> void* {
        void* p = w + off;
        off += (bytes + 255) & ~(size_t)255;
        return p;
    };
    int* flag = (int*)carve(256);
    int* deg = (int*)carve((size_t)3 * NN * 4);
    int* rowptr = (int*)carve((size_t)3 * NN * 4);
    int* cursor = (int*)carve((size_t)3 * NN * 4);
    int* bsum = (int*)carve((size_t)3 * 64 * 4);
    float4* g1v4 = (float4*)carve((size_t)3 * NN * 16);
    float4* g2v4 = (float4*)carve((size_t)3 * NN * 16);
    int2* csr_se = (int2*)carve((size_t)3 * EE * 8);
    float* fw = (float*)carve((size_t)WTOT * 4);
    unsigned short* wb = (unsigned short*)carve((size_t)WB_TOT * 2);
    unsigned short* x16 = (unsigned short*)carve((size_t)NN * 64 * 2);
    unsigned short* raw2_16 = (unsigned short*)carve((size_t)NN * 192 * 2);
    int* mark = (int*)carve((size_t)NN * 4);
    int* slotof = (int*)carve((size_t)NN * 4);
    int* cntp = (int*)carve(256);
    float* z2 = (float*)carve((size_t)BB * 576 * 4);

    hipMemsetAsync(deg, 0, (size_t)3 * NN * 4, stream);
    hipMemsetAsync(mark, 0, (size_t)NN * 4, stream);
    hipMemsetAsync(cntp, 0, 4, stream);

    k_sniff<<<1, 64, 0, stream>>>((const unsigned short*)h, flag);
    k_convert<<<(WTOT + 1023) / 1024, 1024, 0, stream>>>(
        flag, d_in[8], d_in[9],
        d_in[10], d_in[16], d_in[22],
        d_in[11], d_in[17], d_in[23],
        d_in[12], d_in[18], d_in[24],
        d_in[13], d_in[19], d_in[25],
        d_in[14], d_in[20], d_in[26],
        d_in[15], d_in[21], d_in[27],
        d_in[28], d_in[29], d_in[30], d_in[31], fw);
    k_convert16<<<(WB_TOT + 255) / 256, 256, 0, stream>>>(flag, d_in[8], d_in[12], d_in[18],
                                                          d_in[24], wb);

    dim3 ge(3125, 3);
    k_deg<<<ge, 256, 0, stream>>>(dst1, dst2, dst3, deg);
    k_dnorm<<<(3 * NN + 255) / 256, 256, 0, stream>>>(deg, (float*)g1v4, (float*)g2v4);
    dim3 gsc(SCAN_BLK, 3);
    k_scan1<<<gsc, 256, 0, stream>>>(deg, rowptr, bsum);
    k_scan2<<<3, 64, 0, stream>>>(bsum);
    k_scan3<<<gsc, 256, 0, stream>>>(rowptr, cursor, bsum);

    k_input<<<3125, 256, 0, stream>>>(flag, h, wb, fw, x16, g1v4);
    k_scatter<<<ge, 256, 0, stream>>>(src1, src2, src3, dst1, dst2, dst3, cursor, g1v4, fw, csr_se);

    dim3 gl(3125, 3);
    k_layer1<<<gl, 1024, 0, stream>>>(x16, csr_se, rowptr, deg, wb, raw2_16);
    k_p2<<<3125, 1024, 0, stream>>>(raw2_16, fw, g2v4);
    k_mark<<<(BB + 255) / 256, 256, 0, stream>>>(nodes, mark, slotof, cntp);
    k_layer2<<<gl, 1024, 0, stream>>>(raw2_16, csr_se, rowptr, deg, g2v4, fw, mark, slotof, z2);
    k_final<<<BB / 4, 256, 0, stream>>>(flag, nodes, slotof, z2, raw2_16, x16, h, fw, d_out);
}